// Round 8
// baseline (6133.832 us; speedup 1.0000x reference)
//
#include <hip/hip_runtime.h>
#include <math.h>

#define DD 64
#define NSWEEP 8

__device__ __forceinline__ float rdlane(float v, int l) {
    return __int_as_float(__builtin_amdgcn_readlane(__float_as_int(v), l));
}
__device__ __forceinline__ float bperm(int paddr, float v) {
    return __int_as_float(__builtin_amdgcn_ds_bpermute(paddr, __float_as_int(v)));
}

// Cholesky (Xs = L L^T) + one-sided Jacobi on columns of L, register-resident.
// L = U Sigma V^T => Xs = U Sigma^2 U^T: lambda_j = ||w_j||^2 at convergence.
// out = sum_j w_j w_j^T * log(clip(lam_j,1e-7)) / lam_j.
__global__ __launch_bounds__(64, 2)
void logeig_chol1s_kernel(const float* __restrict__ X, float* __restrict__ out, int nb) {
    __shared__ float M[DD][DD + 1];   // transpose staging + epilogue buffer
    __shared__ float sc[DD];

    const int b = blockIdx.x;
    if (b >= nb) return;
    const int lane = threadIdx.x & 63;
    const float* Xb = X + (size_t)b * DD * DD;

    // Stage X coalesced, then w = column `lane` of Xs = 0.5*(X + X^T)
    #pragma unroll
    for (int e = 0; e < DD; ++e) M[e][lane] = Xb[e * DD + lane];
    __syncthreads();

    float w[DD];
    #pragma unroll
    for (int e = 0; e < DD; ++e) w[e] = 0.5f * (M[e][lane] + M[lane][e]);

    // ---- In-wave right-looking Cholesky: lane j ends owning column j of L ----
    #pragma unroll
    for (int k = 0; k < DD; ++k) {
        const float pivot = rdlane(w[k], k);          // A'[k][k] > 0 (SPD)
        const float rinv  = 1.0f / sqrtf(pivot);
        const float ljk   = w[k] * rinv;              // L[lane][k], valid lane >= k
        const bool  gtk   = (lane > k);
        const bool  eqk   = (lane == k);
        #pragma unroll
        for (int e = k; e < DD; ++e) {
            const float lek = rdlane(w[e], k) * rinv; // L[e][k] (uniform)
            const float upd = fmaf(-lek, ljk, w[e]);
            w[e] = eqk ? lek : (gtk ? upd : w[e]);
        }
    }
    // Zero strict upper part
    #pragma unroll
    for (int e = 0; e < DD - 1; ++e)
        w[e] = (e < lane) ? 0.0f : w[e];

    // Initial column norm^2 (maintained incrementally)
    float nown;
    {
        float n0 = 0.f, n1 = 0.f;
        #pragma unroll
        for (int e = 0; e < DD; e += 2) {
            n0 = fmaf(w[e],     w[e],     n0);
            n1 = fmaf(w[e + 1], w[e + 1], n1);
        }
        nown = n0 + n1;
    }

    const int lane4 = lane << 2;

    for (int sw = 0; sw < NSWEEP; ++sw) {
        bool sweep_rotated = false;
        for (int m = 1; m < DD; ++m) {
            const int paddr = lane4 ^ (m << 2);   // partner*4 (XOR pairing)

            // Pull partner's column once; pin into VGPRs so the compiler
            // cannot rematerialize (re-issue) the bpermutes in the update
            // loop (round-7 disasm evidence: VGPR_Count=80 => oth not live).
            float oth[DD];
            #pragma unroll
            for (int e = 0; e < DD; ++e) oth[e] = bperm(paddr, w[e]);
            #pragma unroll
            for (int e = 0; e < DD; ++e) asm volatile("" : "+v"(oth[e]));

            // d = w . oth (identical summation order both lanes -> bitwise-equal)
            float d0 = 0.f, d1 = 0.f;
            #pragma unroll
            for (int e = 0; e < DD; e += 2) {
                d0 = fmaf(w[e],     oth[e],     d0);
                d1 = fmaf(w[e + 1], oth[e + 1], d1);
            }
            const float d    = d0 + d1;
            const float noth = bperm(paddr, nown);

            const bool dorot = (d * d > 1e-14f * nown * noth);
            if (__any(dorot)) {
                sweep_rotated = true;
                const bool  islo = (paddr > lane4);   // low lane plays p
                const float app  = islo ? nown : noth;
                const float aqq  = islo ? noth : nown;
                float tau = (aqq - app) * 0.5f / d;
                float t   = 1.0f / (fabsf(tau) + sqrtf(fmaf(tau, tau, 1.0f)));
                t = copysignf(t, tau);
                float c = 1.0f / sqrtf(fmaf(t, t, 1.0f));
                float s = t * c;
                float tsgn = islo ? -t : t;           // nown' = nown -+ t*d
                if (!islo) s = -s;
                if (!dorot) { c = 1.0f; s = 0.0f; tsgn = 0.0f; }
                nown = fmaf(tsgn, d, nown);
                #pragma unroll
                for (int e = 0; e < DD; ++e)
                    w[e] = fmaf(-s, oth[e], c * w[e]);
            }
        }
        // A sweep with zero rotations is identity; all later sweeps would be
        // identity too (deterministic) -> skipping them is output-identical.
        if (!sweep_rotated) break;
    }

    // lambda_j = ||w_j||^2 (recomputed fresh)
    float n0 = 0.f, n1 = 0.f;
    #pragma unroll
    for (int e = 0; e < DD; e += 2) {
        n0 = fmaf(w[e],     w[e],     n0);
        n1 = fmaf(w[e + 1], w[e + 1], n1);
    }
    const float nn  = n0 + n1;                        // = lambda_j
    const float scl = logf(fmaxf(nn, 1e-7f)) / nn;    // log(clip(lam))/lam

    // Epilogue: out[r][c] = sum_j W[r][j] * scl_j * W[c][j]
    __syncthreads();
    #pragma unroll
    for (int e = 0; e < DD; ++e) M[e][lane] = w[e];
    sc[lane] = scl;
    __syncthreads();

    float vrow[DD];
    #pragma unroll
    for (int j = 0; j < DD; ++j) vrow[j] = M[lane][j] * sc[j];

    float* Ob = out + (size_t)b * DD * DD;
    #pragma unroll 4
    for (int r = 0; r < DD; ++r) {
        float a0 = 0.f, a1 = 0.f;
        #pragma unroll
        for (int j = 0; j < DD; j += 2) {
            a0 = fmaf(M[r][j],     vrow[j],     a0);
            a1 = fmaf(M[r][j + 1], vrow[j + 1], a1);
        }
        Ob[r * DD + lane] = a0 + a1;
    }
}

extern "C" void kernel_launch(void* const* d_in, const int* in_sizes, int n_in,
                              void* d_out, int out_size, void* d_ws, size_t ws_size,
                              hipStream_t stream) {
    (void)n_in; (void)d_ws; (void)ws_size; (void)out_size;
    const float* X = (const float*)d_in[0];
    float* out = (float*)d_out;
    int nb = in_sizes[0] / (DD * DD);
    dim3 grid(nb);
    dim3 block(DD);
    hipLaunchKernelGGL(logeig_chol1s_kernel, grid, block, 0, stream, X, out, nb);
}